// Round 8
// baseline (49.206 us; speedup 1.0000x reference)
//
#include <hip/hip_runtime.h>
#include <stdint.h>

#define T_DIM 64
#define IN_DIM 4096
#define OUT_DIM 8192
#define NGROUPS 16
#define GS 256
#define SPLITK 8
#define KCHUNK (IN_DIM / SPLITK)    // 512
#define BK 64                       // ints per row per stage (256B granule)
#define NSTAGES (KCHUNK / BK)       // 8
#define NTILE 128                   // output cols per block
#define WCOLS 16                    // output cols per wave (one B-frag)
#define OUT_ELEMS (T_DIM * OUT_DIM) // 524288
#define PART_OFF (1u << 20)         // partials at d_ws + 1MB (xb in first 512KB)

typedef __attribute__((ext_vector_type(4))) float f32x4;
typedef __attribute__((ext_vector_type(8))) __bf16 bf16x8;

__global__ void zero_kernel(float4* __restrict__ p, int n4) {
    int i = blockIdx.x * blockDim.x + threadIdx.x;
    if (i < n4) p[i] = make_float4(0.f, 0.f, 0.f, 0.f);
}

__global__ void cvt_kernel(const float* __restrict__ x, __bf16* __restrict__ xb, int n) {
    int i = (blockIdx.x * blockDim.x + threadIdx.x) * 8;
    if (i < n) {
        float4 f0 = *(const float4*)(x + i);
        float4 f1 = *(const float4*)(x + i + 4);
        bf16x8 o;
        o[0] = (__bf16)f0.x; o[1] = (__bf16)f0.y; o[2] = (__bf16)f0.z; o[3] = (__bf16)f0.w;
        o[4] = (__bf16)f1.x; o[5] = (__bf16)f1.y; o[6] = (__bf16)f1.z; o[7] = (__bf16)f1.w;
        *(bf16x8*)(xb + i) = o;
    }
}

// sum 8 bf16 partial slices -> f32 output. thread i handles 8 elems.
__global__ void reduce_kernel(const __bf16* __restrict__ part, float* __restrict__ out, int n8) {
    int i = blockIdx.x * blockDim.x + threadIdx.x;
    if (i < n8) {
        float s[8] = {};
        #pragma unroll
        for (int k = 0; k < SPLITK; ++k) {
            bf16x8 v = *(const bf16x8*)(part + (size_t)k * OUT_ELEMS + (size_t)i * 8);
            #pragma unroll
            for (int j = 0; j < 8; ++j) s[j] += (float)v[j];
        }
        float4 o0 = make_float4(s[0], s[1], s[2], s[3]);
        float4 o1 = make_float4(s[4], s[5], s[6], s[7]);
        *(float4*)(out + (size_t)i * 8)     = o0;
        *(float4*)(out + (size_t)i * 8 + 4) = o1;
    }
}

__device__ __forceinline__ void gld_lds16(const int* g, int* l) {
    __builtin_amdgcn_global_load_lds(
        (const __attribute__((address_space(1))) void*)g,
        (__attribute__((address_space(3))) void*)l, 16, 0, 0);
}

// Block = 8 waves (512 thr), N-tile = 128 cols; each wave owns 16 cols (one
// B-frag) and stages its own 16 weight rows into a private LDS slice (no
// barriers). Per stage: issue group(s+1) = [4 gld_lds + 8 x loads], counted
// s_waitcnt vmcnt(12) releases compute(s) while group(s+1) stays in flight.
// LDS = 2 x 32KB = 64KB -> 2 blocks/CU = 4 waves/SIMD (latency hiding: the
// 1-deep prefetch only covers ~350cy of ~900cy HBM latency; cross-wave
// overlap at 4 waves/SIMD covers the rest). grid = (64, SPLITK) = 512.
template<bool PART>
__global__ __launch_bounds__(512, 4)
void qgemm(const float* __restrict__ x, const __bf16* __restrict__ xb,
           const int* __restrict__ qw, const float* __restrict__ qrange,
           const float* __restrict__ qmin, float* __restrict__ out,
           __bf16* __restrict__ bpart)
{
    __shared__ int lds[2][NTILE][BK];   // 2 x 32KB double buffer

    const int lane  = threadIdx.x & 63;
    const int wv    = threadIdx.x >> 6;   // 0..7
    const int r     = lane & 15;          // fragment row/col index
    const int q4    = lane >> 4;          // k-slot (0..3)
    const int obase = blockIdx.x * NTILE;
    const int ks    = blockIdx.y;
    const int kbase = ks * KCHUNK;
    const int rl0   = wv * WCOLS + r;     // local weight row
    const int o0    = obase + rl0;        // output col

    // 2 quant groups per K-chunk (KCHUNK=512, GS=256); group = s>>2
    float sc[2], mi[2];
    #pragma unroll
    for (int g = 0; g < 2; ++g) {
        sc[g] = qrange[o0 * NGROUPS + ks * 2 + g];
        mi[g] = qmin[o0 * NGROUPS + ks * 2 + g];
    }

    const __bf16* xrow = xb + (size_t)r * IN_DIM + kbase + q4 * 8;

    f32x4 acc[4] = {};
    bf16x8 xf[2][4][2];   // [buf][m][kk] double buffer; indices compile-time

    // Stage the wave's 16 rows x 256B: 4 gld_lds, each = 4 rows x 256B
    // (16 lanes per row). LDS dest linear; XOR swizzle (slot^(row&7)) applied
    // on the SOURCE chunk and again on the read.
    auto stage_w = [&](int s, int b) {
        #pragma unroll
        for (int i = 0; i < 4; ++i) {
            const int rl = wv * WCOLS + i * 4 + (lane >> 4);
            const int c  = (lane & 15) ^ (rl & 7);
            const int* gp = qw + (size_t)(obase + rl) * IN_DIM + kbase + s * BK + c * 4;
            gld_lds16(gp, &lds[b][wv * WCOLS + i * 4][0]);
        }
    };

    auto xload = [&](int s, int buf) {
        #pragma unroll
        for (int m = 0; m < 4; ++m) {
            #pragma unroll
            for (int kk = 0; kk < 2; ++kk) {
                const int koff = s * BK + kk * 32;
                xf[buf][m][kk] = *(const bf16x8*)(xrow + (size_t)(m * 16) * IN_DIM + koff);
            }
        }
    };

    auto compute = [&](int s, int b, int xbuf) {
        const int g = s >> 2;
        const float s0 = sc[g], m0 = mi[g];
        #pragma unroll
        for (int kk = 0; kk < 2; ++kk) {
            const int t  = q4 * 2;
            const int p0 = kk * 8 + ((t    ) ^ (rl0 & 7));
            const int p1 = kk * 8 + ((t + 1) ^ (rl0 & 7));
            int4 c0 = *(const int4*)&lds[b][rl0][p0 * 4];
            int4 c1 = *(const int4*)&lds[b][rl0][p1 * 4];
            bf16x8 bfr;
            bfr[0] = (__bf16)((float)c0.x * s0 + m0);
            bfr[1] = (__bf16)((float)c0.y * s0 + m0);
            bfr[2] = (__bf16)((float)c0.z * s0 + m0);
            bfr[3] = (__bf16)((float)c0.w * s0 + m0);
            bfr[4] = (__bf16)((float)c1.x * s0 + m0);
            bfr[5] = (__bf16)((float)c1.y * s0 + m0);
            bfr[6] = (__bf16)((float)c1.z * s0 + m0);
            bfr[7] = (__bf16)((float)c1.w * s0 + m0);
            #pragma unroll
            for (int m = 0; m < 4; ++m)
                acc[m] = __builtin_amdgcn_mfma_f32_16x16x32_bf16(xf[xbuf][m][kk], bfr, acc[m], 0, 0, 0);
        }
    };

    // prologue: group(0) in flight
    stage_w(0, 0);
    xload(0, 0);
    #pragma unroll
    for (int s = 0; s < NSTAGES; ++s) {
        if (s + 1 < NSTAGES) {
            stage_w(s + 1, (s + 1) & 1);   // group(s+1): 4 gld_lds ...
            xload(s + 1, (s + 1) & 1);     //   ... + 8 x loads = 12 vmem ops
            asm volatile("s_waitcnt vmcnt(12)" ::: "memory");
        } else {
            asm volatile("s_waitcnt vmcnt(0)" ::: "memory");
        }
        __builtin_amdgcn_sched_barrier(0);
        compute(s, s & 1, s & 1);
    }

    // D layout: col = lane&15 (-> o0), row = q4*4 + j, per m-tile of 16
    if constexpr (PART) {
        // bf16 partials into this ks's private slice — no atomics
        __bf16* part = bpart + (size_t)ks * OUT_ELEMS;
        #pragma unroll
        for (int m = 0; m < 4; ++m) {
            #pragma unroll
            for (int j = 0; j < 4; ++j) {
                const int t = m * 16 + q4 * 4 + j;
                part[(size_t)t * OUT_DIM + o0] = (__bf16)acc[m][j];
            }
        }
    } else {
        #pragma unroll
        for (int m = 0; m < 4; ++m) {
            #pragma unroll
            for (int j = 0; j < 4; ++j) {
                const int t = m * 16 + q4 * 4 + j;
                unsafeAtomicAdd(&out[(size_t)t * OUT_DIM + o0], acc[m][j]);
            }
        }
    }
}

extern "C" void kernel_launch(void* const* d_in, const int* in_sizes, int n_in,
                              void* d_out, int out_size, void* d_ws, size_t ws_size,
                              hipStream_t stream)
{
    const float* x      = (const float*)d_in[0];
    const int*   qw     = (const int*)d_in[1];
    const float* qrange = (const float*)d_in[2];
    const float* qmin   = (const float*)d_in[3];
    float* out = (float*)d_out;

    const int nx = T_DIM * IN_DIM;                  // 262144
    const size_t xb_bytes   = (size_t)nx * sizeof(unsigned short);            // 512KB
    const size_t part_bytes = (size_t)SPLITK * OUT_ELEMS * sizeof(short);     // 8MB

    if (ws_size >= PART_OFF + part_bytes && ws_size >= xb_bytes) {
        __bf16* xbp  = (__bf16*)d_ws;
        __bf16* part = (__bf16*)((char*)d_ws + PART_OFF);
        cvt_kernel<<<dim3(nx / 8 / 256), dim3(256), 0, stream>>>(x, xbp, nx);
        qgemm<true><<<dim3(OUT_DIM / NTILE, SPLITK), dim3(512), 0, stream>>>(
            x, xbp, qw, qrange, qmin, out, part);
        const int n8 = OUT_ELEMS / 8;
        reduce_kernel<<<dim3(n8 / 256), dim3(256), 0, stream>>>(part, out, n8);
    } else {
        // fallback: atomic path (requires zeroed output)
        const int n4 = out_size / 4;
        zero_kernel<<<dim3((n4 + 255) / 256), dim3(256), 0, stream>>>((float4*)d_out, n4);
        __bf16* xbp = (__bf16*)d_ws;
        cvt_kernel<<<dim3(nx / 8 / 256), dim3(256), 0, stream>>>(x, xbp, nx);
        qgemm<false><<<dim3(OUT_DIM / NTILE, SPLITK), dim3(512), 0, stream>>>(
            x, xbp, qw, qrange, qmin, out, nullptr);
    }
}

// Round 9
// 34.627 us; speedup vs baseline: 1.4210x; 1.4210x over previous
//
#include <hip/hip_runtime.h>
#include <stdint.h>

#define T_DIM 64
#define IN_DIM 4096
#define OUT_DIM 8192
#define NGROUPS 16
#define GS 256
#define SPLITK 8
#define KCHUNK (IN_DIM / SPLITK)    // 512
#define BK 32                       // ints per row per stage (128B granule)
#define NSTAGES (KCHUNK / BK)       // 16
#define NTILE 256                   // output cols per block
#define WCOLS 32                    // output cols per wave (two B-frags)
#define OUT_ELEMS (T_DIM * OUT_DIM) // 524288
#define PART_OFF (1u << 20)         // partials at d_ws + 1MB (xb in first 512KB)

typedef __attribute__((ext_vector_type(4))) float f32x4;
typedef __attribute__((ext_vector_type(8))) __bf16 bf16x8;

__global__ void zero_kernel(float4* __restrict__ p, int n4) {
    int i = blockIdx.x * blockDim.x + threadIdx.x;
    if (i < n4) p[i] = make_float4(0.f, 0.f, 0.f, 0.f);
}

__global__ void cvt_kernel(const float* __restrict__ x, __bf16* __restrict__ xb, int n) {
    int i = (blockIdx.x * blockDim.x + threadIdx.x) * 8;
    if (i < n) {
        float4 f0 = *(const float4*)(x + i);
        float4 f1 = *(const float4*)(x + i + 4);
        bf16x8 o;
        o[0] = (__bf16)f0.x; o[1] = (__bf16)f0.y; o[2] = (__bf16)f0.z; o[3] = (__bf16)f0.w;
        o[4] = (__bf16)f1.x; o[5] = (__bf16)f1.y; o[6] = (__bf16)f1.z; o[7] = (__bf16)f1.w;
        *(bf16x8*)(xb + i) = o;
    }
}

// sum 8 bf16 partial slices -> f32 output. thread i handles 8 elems.
__global__ void reduce_kernel(const __bf16* __restrict__ part, float* __restrict__ out, int n8) {
    int i = blockIdx.x * blockDim.x + threadIdx.x;
    if (i < n8) {
        float s[8] = {};
        #pragma unroll
        for (int k = 0; k < SPLITK; ++k) {
            bf16x8 v = *(const bf16x8*)(part + (size_t)k * OUT_ELEMS + (size_t)i * 8);
            #pragma unroll
            for (int j = 0; j < 8; ++j) s[j] += (float)v[j];
        }
        *(float4*)(out + (size_t)i * 8)     = make_float4(s[0], s[1], s[2], s[3]);
        *(float4*)(out + (size_t)i * 8 + 4) = make_float4(s[4], s[5], s[6], s[7]);
    }
}

__device__ __forceinline__ void gld_lds16(const int* g, int* l) {
    __builtin_amdgcn_global_load_lds(
        (const __attribute__((address_space(1))) void*)g,
        (__attribute__((address_space(3))) void*)l, 16, 0, 0);
}

// Block = 8 waves (512 thr), N-tile = 256. KEY CHANGE (R9): the x panel
// (64 x 512 bf16 = 64KB) is staged into LDS ONCE in the prologue and shared
// by all waves -> x global traffic drops 128MB -> 16MB (it was duplicated
// per-wave before; that duplication explains R1..R8's throughput ladder).
// Weights: BK=32 (128B/row granule), wave-private double-buffered slices,
// counted vmcnt(4), no barriers in the K-loop (one __syncthreads in prologue).
// All LDS tiles use the chunk^(row&7) XOR swizzle (<=2-way banks, free):
// phys 16B-chunk j holds logical chunk j^(row&7), applied at SOURCE address
// (gld_lds dest stays linear) and again on the ds_read.
// LDS = 64KB x + 2x32KB w = 128KB -> 1 block/CU. grid = (32, SPLITK) = 256.
template<bool PART>
__global__ __launch_bounds__(512, 2)
void qgemm(const __bf16* __restrict__ xb,
           const int* __restrict__ qw, const float* __restrict__ qrange,
           const float* __restrict__ qmin, float* __restrict__ out,
           __bf16* __restrict__ bpart)
{
    __shared__ int xs[64 * 256];          // x panel: 64 rows x 1024B (64KB)
    __shared__ int wl[2][NTILE * BK];     // weights: 2 x 32KB double buffer

    const int lane  = threadIdx.x & 63;
    const int wv    = threadIdx.x >> 6;   // 0..7
    const int r     = lane & 15;          // fragment row/col index
    const int q4    = lane >> 4;          // k-slot (0..3)
    const int obase = blockIdx.x * NTILE;
    const int ks    = blockIdx.y;
    const int kbase = ks * KCHUNK;
    const int rl0   = wv * WCOLS + r;     // local weight row, frag n=0
    const int o0    = obase + rl0;        // output col, frag n=0
    const int o1    = o0 + 16;            // output col, frag n=1

    // 2 quant groups per K-chunk (KCHUNK=512, GS=256); group = s>>3
    float sc[2][2], mi[2][2];             // [n][g]
    #pragma unroll
    for (int g = 0; g < 2; ++g) {
        sc[0][g] = qrange[o0 * NGROUPS + ks * 2 + g];
        mi[0][g] = qmin[o0 * NGROUPS + ks * 2 + g];
        sc[1][g] = qrange[o1 * NGROUPS + ks * 2 + g];
        mi[1][g] = qmin[o1 * NGROUPS + ks * 2 + g];
    }

    f32x4 acc[4][2] = {};

    // ---- x prologue: each wave stages 8 full rows (1024B = one gld_lds each).
    // dest wave-uniform (row base), lane adds lane*16B; source chunk = lane^(row&7).
    {
        #pragma unroll
        for (int i = 0; i < 8; ++i) {
            const int row = i * 8 + wv;
            const __bf16* gp = xb + (size_t)row * IN_DIM + kbase
                                  + ((lane ^ (row & 7)) << 3);
            gld_lds16((const int*)gp, &xs[row * 256]);
        }
    }

    // ---- weight staging: wave's 32 rows x 128B = 4 gld_lds (8 rows each).
    auto stage_w = [&](int s, int b) {
        #pragma unroll
        for (int i = 0; i < 4; ++i) {
            const int row = wv * WCOLS + i * 8 + (lane >> 3);
            const int c   = (lane & 7) ^ (row & 7);
            const int* gp = qw + (size_t)(obase + row) * IN_DIM + kbase + s * BK
                               + (c << 2);
            gld_lds16(gp, &wl[b][(wv * WCOLS + i * 8) * BK]);
        }
    };

    auto compute = [&](int s, int b) {
        const int g = s >> 3;
        // A fragments from shared x panel (reused across both B-frags)
        bf16x8 a[4];
        #pragma unroll
        for (int m = 0; m < 4; ++m) {
            const int rr = m * 16 + r;
            const int p  = (s * 4 + q4) ^ (rr & 7);   // phys 16B chunk
            a[m] = *(const bf16x8*)&xs[rr * 256 + p * 4];
        }
        #pragma unroll
        for (int n = 0; n < 2; ++n) {
            const int rl = rl0 + n * 16;
            const int p0 = ((q4 * 2    ) ^ (rl & 7)) * 4;
            const int p1 = ((q4 * 2 + 1) ^ (rl & 7)) * 4;
            int4 c0 = *(const int4*)&wl[b][rl * BK + p0];
            int4 c1 = *(const int4*)&wl[b][rl * BK + p1];
            const float s0 = sc[n][g], m0 = mi[n][g];
            bf16x8 bfr;
            bfr[0] = (__bf16)((float)c0.x * s0 + m0);
            bfr[1] = (__bf16)((float)c0.y * s0 + m0);
            bfr[2] = (__bf16)((float)c0.z * s0 + m0);
            bfr[3] = (__bf16)((float)c0.w * s0 + m0);
            bfr[4] = (__bf16)((float)c1.x * s0 + m0);
            bfr[5] = (__bf16)((float)c1.y * s0 + m0);
            bfr[6] = (__bf16)((float)c1.z * s0 + m0);
            bfr[7] = (__bf16)((float)c1.w * s0 + m0);
            #pragma unroll
            for (int m = 0; m < 4; ++m)
                acc[m][n] = __builtin_amdgcn_mfma_f32_16x16x32_bf16(a[m], bfr, acc[m][n], 0, 0, 0);
        }
    };

    stage_w(0, 0);
    __syncthreads();   // one-time: x panel (and w(0)) visible to all waves

    #pragma unroll
    for (int s = 0; s < NSTAGES; ++s) {
        if (s + 1 < NSTAGES) {
            stage_w(s + 1, (s + 1) & 1);   // 4 gld_lds for next stage
            // outstanding = w(s) leftover? no: steady state has w(s+1)=4 only
            // after the wait; counted wait keeps w(s+1) in flight.
            asm volatile("s_waitcnt vmcnt(4)" ::: "memory");
        } else {
            asm volatile("s_waitcnt vmcnt(0)" ::: "memory");
        }
        __builtin_amdgcn_sched_barrier(0);
        compute(s, s & 1);
    }

    // D layout: col = lane&15 (-> o0/o1), row = q4*4 + j, per m-tile of 16
    if constexpr (PART) {
        __bf16* part = bpart + (size_t)ks * OUT_ELEMS;
        #pragma unroll
        for (int m = 0; m < 4; ++m) {
            #pragma unroll
            for (int j = 0; j < 4; ++j) {
                const int t = m * 16 + q4 * 4 + j;
                part[(size_t)t * OUT_DIM + o0] = (__bf16)acc[m][0][j];
                part[(size_t)t * OUT_DIM + o1] = (__bf16)acc[m][1][j];
            }
        }
    } else {
        #pragma unroll
        for (int m = 0; m < 4; ++m) {
            #pragma unroll
            for (int j = 0; j < 4; ++j) {
                const int t = m * 16 + q4 * 4 + j;
                unsafeAtomicAdd(&out[(size_t)t * OUT_DIM + o0], acc[m][0][j]);
                unsafeAtomicAdd(&out[(size_t)t * OUT_DIM + o1], acc[m][1][j]);
            }
        }
    }
}

extern "C" void kernel_launch(void* const* d_in, const int* in_sizes, int n_in,
                              void* d_out, int out_size, void* d_ws, size_t ws_size,
                              hipStream_t stream)
{
    const float* x      = (const float*)d_in[0];
    const int*   qw     = (const int*)d_in[1];
    const float* qrange = (const float*)d_in[2];
    const float* qmin   = (const float*)d_in[3];
    float* out = (float*)d_out;

    const int nx = T_DIM * IN_DIM;                  // 262144
    const size_t xb_bytes   = (size_t)nx * sizeof(unsigned short);        // 512KB
    const size_t part_bytes = (size_t)SPLITK * OUT_ELEMS * sizeof(short); // 8MB

    __bf16* xbp = (__bf16*)d_ws;
    cvt_kernel<<<dim3(nx / 8 / 256), dim3(256), 0, stream>>>(x, xbp, nx);

    if (ws_size >= PART_OFF + part_bytes) {
        __bf16* part = (__bf16*)((char*)d_ws + PART_OFF);
        qgemm<true><<<dim3(OUT_DIM / NTILE, SPLITK), dim3(512), 0, stream>>>(
            xbp, qw, qrange, qmin, out, part);
        const int n8 = OUT_ELEMS / 8;
        reduce_kernel<<<dim3(n8 / 256), dim3(256), 0, stream>>>(part, out, n8);
    } else {
        // fallback: atomic path (requires zeroed output)
        const int n4 = out_size / 4;
        zero_kernel<<<dim3((n4 + 255) / 256), dim3(256), 0, stream>>>((float4*)d_out, n4);
        qgemm<false><<<dim3(OUT_DIM / NTILE, SPLITK), dim3(512), 0, stream>>>(
            xbp, qw, qrange, qmin, out, nullptr);
    }
}

// Round 11
// 33.502 us; speedup vs baseline: 1.4688x; 1.0336x over previous
//
#include <hip/hip_runtime.h>
#include <stdint.h>

#define T_DIM 64
#define IN_DIM 4096
#define OUT_DIM 8192
#define NGROUPS 16
#define GS 256
#define SPLITK 8
#define KCHUNK (IN_DIM / SPLITK)    // 512
#define BK 32                       // ints per row per stage (128B granule)
#define NSTAGES (KCHUNK / BK)       // 16
#define NTILE 256                   // output cols per block
#define WCOLS 32                    // output cols per wave (two B-frags)
#define OUT_ELEMS (T_DIM * OUT_DIM) // 524288
#define PART_OFF (1u << 20)         // partials at d_ws + 1MB

typedef __attribute__((ext_vector_type(4))) float f32x4;
typedef __attribute__((ext_vector_type(8))) __bf16 bf16x8;

__global__ void zero_kernel(float4* __restrict__ p, int n4) {
    int i = blockIdx.x * blockDim.x + threadIdx.x;
    if (i < n4) p[i] = make_float4(0.f, 0.f, 0.f, 0.f);
}

// sum 8 bf16 partial slices -> f32 output. thread i handles 8 elems.
__global__ void reduce_kernel(const __bf16* __restrict__ part, float* __restrict__ out, int n8) {
    int i = blockIdx.x * blockDim.x + threadIdx.x;
    if (i < n8) {
        float s[8] = {};
        #pragma unroll
        for (int k = 0; k < SPLITK; ++k) {
            bf16x8 v = *(const bf16x8*)(part + (size_t)k * OUT_ELEMS + (size_t)i * 8);
            #pragma unroll
            for (int j = 0; j < 8; ++j) s[j] += (float)v[j];
        }
        *(float4*)(out + (size_t)i * 8)     = make_float4(s[0], s[1], s[2], s[3]);
        *(float4*)(out + (size_t)i * 8 + 4) = make_float4(s[4], s[5], s[6], s[7]);
    }
}

__device__ __forceinline__ void gld_lds16(const int* g, int* l) {
    __builtin_amdgcn_global_load_lds(
        (const __attribute__((address_space(1))) void*)g,
        (__attribute__((address_space(3))) void*)l, 16, 0, 0);
}

// Block = 8 waves (512 thr), N-tile = 256, K-chunk = 512 (SPLITK=8).
// Fused cvt: each block stages its own x panel (64 x 512) straight from the
// f32 input (f32 x = 1MB, L2/L3-resident; nominal re-reads are cache-served):
// thread t owns row t>>3 and 8 logical 16B chunks lc = (t&7)*8 + i, i=0..7
// (8 thr/row x 8 chunks = 64 chunks = full 1024B row  <- R10 bug was 4/thread
// = half panel uninitialized -> NaN). Convert f32x8 -> bf16x8, ds_write_b128
// to phys chunk pc = lc ^ (row&7) (same layout R9's verified read expects).
// K-loop unchanged from R9: wave-private double-buffered weight slices,
// counted vmcnt(4), XOR swizzle chunk^(row&7) on both LDS tiles, bf16
// split-K partials + reduce kernel (no atomics).
// LDS = 64KB x + 2x32KB w = 128KB -> 1 block/CU. grid = (32, SPLITK) = 256.
template<bool PART>
__global__ __launch_bounds__(512, 2)
void qgemm(const float* __restrict__ x,
           const int* __restrict__ qw, const float* __restrict__ qrange,
           const float* __restrict__ qmin, float* __restrict__ out,
           __bf16* __restrict__ bpart)
{
    __shared__ int xs[64 * 256];          // x panel: 64 rows x 1024B (64KB)
    __shared__ int wl[2][NTILE * BK];     // weights: 2 x 32KB double buffer

    const int lane  = threadIdx.x & 63;
    const int wv    = threadIdx.x >> 6;   // 0..7
    const int r     = lane & 15;          // fragment row/col index
    const int q4    = lane >> 4;          // k-slot (0..3)
    const int obase = blockIdx.x * NTILE;
    const int ks    = blockIdx.y;
    const int kbase = ks * KCHUNK;
    const int rl0   = wv * WCOLS + r;     // local weight row, frag n=0
    const int o0    = obase + rl0;        // output col, frag n=0
    const int o1    = o0 + 16;            // output col, frag n=1

    // 2 quant groups per K-chunk (KCHUNK=512, GS=256); group = s>>3
    float sc[2][2], mi[2][2];             // [n][g]
    #pragma unroll
    for (int g = 0; g < 2; ++g) {
        sc[0][g] = qrange[o0 * NGROUPS + ks * 2 + g];
        mi[0][g] = qmin[o0 * NGROUPS + ks * 2 + g];
        sc[1][g] = qrange[o1 * NGROUPS + ks * 2 + g];
        mi[1][g] = qmin[o1 * NGROUPS + ks * 2 + g];
    }

    f32x4 acc[4][2] = {};

    // ---- weight staging: wave's 32 rows x 128B = 4 gld_lds (8 rows each).
    auto stage_w = [&](int s, int b) {
        #pragma unroll
        for (int i = 0; i < 4; ++i) {
            const int row = wv * WCOLS + i * 8 + (lane >> 3);
            const int c   = (lane & 7) ^ (row & 7);
            const int* gp = qw + (size_t)(obase + row) * IN_DIM + kbase + s * BK
                               + (c << 2);
            gld_lds16(gp, &wl[b][(wv * WCOLS + i * 8) * BK]);
        }
    };
    stage_w(0, 0);   // in flight during the x prologue below

    // ---- x prologue (fused cvt): full-coverage version.
    // thread t: row = t>>3 (0..63), 8 chunks lc = (t&7)*8 + i (i=0..7).
    {
        const int row  = threadIdx.x >> 3;        // 0..63
        const int cseg = threadIdx.x & 7;
        const float* xr = x + (size_t)row * IN_DIM + kbase;
        #pragma unroll
        for (int i = 0; i < 8; ++i) {
            const int lc = cseg * 8 + i;          // logical 16B chunk, 0..63
            float4 f0 = *(const float4*)(xr + lc * 8);
            float4 f1 = *(const float4*)(xr + lc * 8 + 4);
            bf16x8 t;
            t[0] = (__bf16)f0.x; t[1] = (__bf16)f0.y; t[2] = (__bf16)f0.z; t[3] = (__bf16)f0.w;
            t[4] = (__bf16)f1.x; t[5] = (__bf16)f1.y; t[6] = (__bf16)f1.z; t[7] = (__bf16)f1.w;
            const int pc = lc ^ (row & 7);        // phys chunk (swizzled)
            *(int4*)&xs[row * 256 + pc * 4] = *(int4*)&t;
        }
    }

    __syncthreads();   // x panel + w(0) visible to all waves

    auto compute = [&](int s, int b) {
        const int g = s >> 3;
        // A fragments from shared x panel (reused across both B-frags)
        bf16x8 a[4];
        #pragma unroll
        for (int m = 0; m < 4; ++m) {
            const int rr = m * 16 + r;
            const int p  = (s * 4 + q4) ^ (rr & 7);   // phys 16B chunk
            a[m] = *(const bf16x8*)&xs[rr * 256 + p * 4];
        }
        #pragma unroll
        for (int n = 0; n < 2; ++n) {
            const int rl = rl0 + n * 16;
            const int p0 = ((q4 * 2    ) ^ (rl & 7)) * 4;
            const int p1 = ((q4 * 2 + 1) ^ (rl & 7)) * 4;
            int4 c0 = *(const int4*)&wl[b][rl * BK + p0];
            int4 c1 = *(const int4*)&wl[b][rl * BK + p1];
            const float s0 = sc[n][g], m0 = mi[n][g];
            bf16x8 bfr;
            bfr[0] = (__bf16)((float)c0.x * s0 + m0);
            bfr[1] = (__bf16)((float)c0.y * s0 + m0);
            bfr[2] = (__bf16)((float)c0.z * s0 + m0);
            bfr[3] = (__bf16)((float)c0.w * s0 + m0);
            bfr[4] = (__bf16)((float)c1.x * s0 + m0);
            bfr[5] = (__bf16)((float)c1.y * s0 + m0);
            bfr[6] = (__bf16)((float)c1.z * s0 + m0);
            bfr[7] = (__bf16)((float)c1.w * s0 + m0);
            #pragma unroll
            for (int m = 0; m < 4; ++m)
                acc[m][n] = __builtin_amdgcn_mfma_f32_16x16x32_bf16(a[m], bfr, acc[m][n], 0, 0, 0);
        }
    };

    #pragma unroll
    for (int s = 0; s < NSTAGES; ++s) {
        if (s + 1 < NSTAGES) {
            stage_w(s + 1, (s + 1) & 1);   // 4 gld_lds for next stage
            asm volatile("s_waitcnt vmcnt(4)" ::: "memory");
        } else {
            asm volatile("s_waitcnt vmcnt(0)" ::: "memory");
        }
        __builtin_amdgcn_sched_barrier(0);
        compute(s, s & 1);
    }

    // D layout: col = lane&15 (-> o0/o1), row = q4*4 + j, per m-tile of 16
    if constexpr (PART) {
        __bf16* part = bpart + (size_t)ks * OUT_ELEMS;
        #pragma unroll
        for (int m = 0; m < 4; ++m) {
            #pragma unroll
            for (int j = 0; j < 4; ++j) {
                const int t = m * 16 + q4 * 4 + j;
                part[(size_t)t * OUT_DIM + o0] = (__bf16)acc[m][0][j];
                part[(size_t)t * OUT_DIM + o1] = (__bf16)acc[m][1][j];
            }
        }
    } else {
        #pragma unroll
        for (int m = 0; m < 4; ++m) {
            #pragma unroll
            for (int j = 0; j < 4; ++j) {
                const int t = m * 16 + q4 * 4 + j;
                unsafeAtomicAdd(&out[(size_t)t * OUT_DIM + o0], acc[m][0][j]);
                unsafeAtomicAdd(&out[(size_t)t * OUT_DIM + o1], acc[m][1][j]);
            }
        }
    }
}

extern "C" void kernel_launch(void* const* d_in, const int* in_sizes, int n_in,
                              void* d_out, int out_size, void* d_ws, size_t ws_size,
                              hipStream_t stream)
{
    const float* x      = (const float*)d_in[0];
    const int*   qw     = (const int*)d_in[1];
    const float* qrange = (const float*)d_in[2];
    const float* qmin   = (const float*)d_in[3];
    float* out = (float*)d_out;

    const size_t part_bytes = (size_t)SPLITK * OUT_ELEMS * sizeof(short); // 8MB

    if (ws_size >= PART_OFF + part_bytes) {
        __bf16* part = (__bf16*)((char*)d_ws + PART_OFF);
        qgemm<true><<<dim3(OUT_DIM / NTILE, SPLITK), dim3(512), 0, stream>>>(
            x, qw, qrange, qmin, out, part);
        const int n8 = OUT_ELEMS / 8;
        reduce_kernel<<<dim3(n8 / 256), dim3(256), 0, stream>>>(part, out, n8);
    } else {
        // fallback: atomic path (requires zeroed output)
        const int n4 = out_size / 4;
        zero_kernel<<<dim3((n4 + 255) / 256), dim3(256), 0, stream>>>((float4*)d_out, n4);
        qgemm<false><<<dim3(OUT_DIM / NTILE, SPLITK), dim3(512), 0, stream>>>(
            x, qw, qrange, qmin, out, nullptr);
    }
}